// Round 2
// baseline (1222.015 us; speedup 1.0000x reference)
//
#include <hip/hip_runtime.h>
#include <stdint.h>

typedef unsigned int u32;
typedef unsigned short u16;

#define NPTS 1000000
#define DIMD 500
#define DIMH 500
#define DIMW 40
#define NVOX 10000000      // DIMD*DIMH*DIMW
#define MAXV 40000
#define MAXP 32
#define NTOT (MAXV * MAXP) // 1,280,000 rows in the flat MLP input
#define PCAP 131072        // capacity for kept points (expected ~42k)
#define OUTV (MAXV * 128)  // 5,120,000 voxel_out elements
#define SCHUNK 4096
#define SNB ((NVOX + SCHUNK - 1) / SCHUNK) // 2442 scan blocks

// ---------- helpers ----------
__device__ __forceinline__ float b2f(u16 h) { return __uint_as_float(((u32)h) << 16); }

__device__ __forceinline__ u16 f2b(float f) {
    u32 u = __float_as_uint(f);
    if ((u & 0x7F800000u) == 0x7F800000u) {           // inf / nan
        u16 h = (u16)(u >> 16);
        if (u & 0x007FFFFFu) h |= 0x40;               // quiet nan
        return h;
    }
    u32 lsb = (u >> 16) & 1u;
    return (u16)((u + 0x7FFFu + lsb) >> 16);          // round-to-nearest-even
}

// dtype-adaptive element load/store. bf==true -> bf16 (u16), else f32.
__device__ __forceinline__ float ld1(const void* p, int i, bool bf) {
    return bf ? b2f(((const u16*)p)[i]) : ((const float*)p)[i];
}
__device__ __forceinline__ float4 ld4(const void* p, int i4, bool bf) {
    if (bf) {
        ushort4 q = ((const ushort4*)p)[i4];
        return make_float4(b2f(q.x), b2f(q.y), b2f(q.z), b2f(q.w));
    }
    return ((const float4*)p)[i4];
}
__device__ __forceinline__ void st1(void* p, size_t i, float v, bool bf) {
    if (bf) ((u16*)p)[i] = f2b(v);
    else ((float*)p)[i] = v;
}

// monotone order-preserving f32 <-> u32 for atomicMax
__device__ __forceinline__ u32 encf(float f) {
    u32 u = __float_as_uint(f);
    return (u & 0x80000000u) ? ~u : (u | 0x80000000u);
}
__device__ __forceinline__ float decf(u32 u) {
    u32 b = (u & 0x80000000u) ? (u & 0x7FFFFFFFu) : ~u;
    return __uint_as_float(b);
}

// exact replica of ((xyz - RANGE_MIN)/VOXEL_SIZE).astype(int32) + validity (f32 ops)
__device__ __forceinline__ bool pkey(float x, float y, float z, int& key) {
    float fx = (x - (-50.0f)) / 0.2f;
    float fy = (y - (-50.0f)) / 0.2f;
    float fz = (z - (-3.0f)) / 0.2f;
    int ix = (int)fx, iy = (int)fy, iz = (int)fz;
    if (ix < 0 || ix >= DIMD || iy < 0 || iy >= DIMH || iz < 0 || iz >= DIMW) return false;
    key = ix * (DIMH * DIMW) + iy * DIMW + iz;
    return true;
}

// ---------- kernels ----------

// Detect input dtype. Even-indexed u16s of `points`: bf16 data -> bf16 values of
// coords in [-50,50] (f32 exponent field ~[100,135]); f32 data -> random low
// mantissa halves (exponent field ~uniform over 0..255, ~20% in window).
__global__ void k_detect(const void* pts, u32* dflag) {
    __shared__ int s[256];
    int t = threadIdx.x;
    const u16* p = (const u16*)pts;
    int good = 0;
    for (int i = 0; i < 16; i++) {
        u16 v = p[(size_t)(t * 16 + i) * 2];
        int e = (v >> 7) & 0xFF;
        if (e >= 90 && e <= 140) good++;
    }
    s[t] = good;
    __syncthreads();
    for (int o = 128; o > 0; o >>= 1) {
        if (t < o) s[t] += s[t + o];
        __syncthreads();
    }
    if (t == 0) *dflag = (s[0] >= (4096 * 3) / 5) ? 1u : 0u;
}

__global__ void k_initmax(u32* maxbuf) {
    int i = blockIdx.x * 256 + threadIdx.x;
    if (i < OUTV) maxbuf[i] = 0x007FFFFFu; // encf(-inf)
}

__global__ void k_hist(const void* __restrict__ pts, const u32* dflag, u32* __restrict__ count) {
    int i = blockIdx.x * 256 + threadIdx.x;
    if (i >= NPTS) return;
    bool bf = *dflag != 0;
    float4 p = ld4(pts, i, bf);
    int key;
    if (pkey(p.x, p.y, p.z, key)) atomicAdd(&count[key], 1u);
}

__global__ void k_scan1(const u32* __restrict__ count, u32* bsums, int* firstkey) {
    __shared__ int s[256];
    __shared__ int sm[256];
    int t = threadIdx.x;
    long base = (long)blockIdx.x * SCHUNK + (long)t * 16;
    int tot = 0, mn = 0x7FFFFFFF;
    for (int i = 0; i < 16; i++) {
        long k = base + i;
        if (k < NVOX && count[k]) { tot++; if ((int)k < mn) mn = (int)k; }
    }
    s[t] = tot; sm[t] = mn;
    __syncthreads();
    for (int o = 128; o > 0; o >>= 1) {
        if (t < o) { s[t] += s[t + o]; sm[t] = min(sm[t], sm[t + o]); }
        __syncthreads();
    }
    if (t == 0) {
        bsums[blockIdx.x] = (u32)s[0];
        if (sm[0] != 0x7FFFFFFF) atomicMin(firstkey, sm[0]);
    }
}

__global__ void k_scan2(const u32* __restrict__ bsums, u32* boffs, u32* totalocc) {
    __shared__ int s[256];
    int t = threadIdx.x;
    const int per = (SNB + 255) / 256;
    int st = t * per, en = min(st + per, (int)SNB);
    int tot = 0;
    for (int i = st; i < en; i++) tot += (int)bsums[i];
    s[t] = tot;
    __syncthreads();
    for (int o = 1; o < 256; o <<= 1) {
        int v = (t >= o) ? s[t - o] : 0;
        __syncthreads();
        s[t] += v;
        __syncthreads();
    }
    int run = s[t] - tot;
    for (int i = st; i < en; i++) { boffs[i] = (u32)run; run += (int)bsums[i]; }
    if (t == 255) *totalocc = (u32)s[255];
}

__global__ void k_scan3(const u32* __restrict__ count, const u32* __restrict__ boffs,
                        const u32* dflag, u16* __restrict__ prefix, void* __restrict__ out) {
    __shared__ int s[256];
    int t = threadIdx.x;
    bool bf = *dflag != 0;
    long base = (long)blockIdx.x * SCHUNK + (long)t * 16;
    int tot = 0;
    for (int i = 0; i < 16; i++) {
        long k = base + i;
        if (k < NVOX && count[k]) tot++;
    }
    s[t] = tot;
    __syncthreads();
    for (int o = 1; o < 256; o <<= 1) {
        int v = (t >= o) ? s[t - o] : 0;
        __syncthreads();
        s[t] += v;
        __syncthreads();
    }
    int run = (int)boffs[blockIdx.x] + s[t] - tot;
    for (int i = 0; i < 16; i++) {
        long k = base + i;
        if (k >= NVOX) break;
        u32 c = count[k];
        prefix[k] = (u16)min(run, 65535);
        if (c) {
            if (run < MAXV) {
                int kk = (int)k;
                int ix = kk / 20000;
                int rem = kk - ix * 20000;
                int iy = rem / 40;
                int iz = rem - iy * 40;
                size_t base_o = (size_t)OUTV + (size_t)run * 4;
                st1(out, base_o + 0, 0.0f, bf);
                st1(out, base_o + 1, (float)ix, bf);
                st1(out, base_o + 2, (float)iy, bf);
                st1(out, base_o + 3, (float)iz, bf);
            }
            run++;
        }
    }
}

__global__ void k_pad(const u32* totalocc, const int* firstkey, const u32* dflag, void* out) {
    int r = blockIdx.x * 256 + threadIdx.x;
    if (r >= MAXV) return;
    if (r < (int)(*totalocc)) return;
    bool bf = *dflag != 0;
    int fk = *firstkey;
    if (fk >= NVOX) fk = 0;
    int ix = fk / 20000, rem = fk - ix * 20000, iy = rem / 40, iz = rem - iy * 40;
    size_t base_o = (size_t)OUTV + (size_t)r * 4;
    st1(out, base_o + 0, 0.0f, bf);
    st1(out, base_o + 1, (float)ix, bf);
    st1(out, base_o + 2, (float)iy, bf);
    st1(out, base_o + 3, (float)iz, bf);
}

__global__ void k_gather(const void* __restrict__ pts, const u16* __restrict__ prefix,
                         const u32* dflag, u32* slotctr, u32* nkept, int* ptvid, float4* ptfeat) {
    int i = blockIdx.x * 256 + threadIdx.x;
    if (i >= NPTS) return;
    bool bf = *dflag != 0;
    float4 p = ld4(pts, i, bf);
    int key;
    if (!pkey(p.x, p.y, p.z, key)) return;
    int r = (int)prefix[key];
    if (r >= MAXV) return;
    u32 slot = atomicAdd(&slotctr[r], 1u);
    if (slot >= MAXP) return;
    u32 idx = atomicAdd(nkept, 1u);
    if (idx >= PCAP) return;
    ptvid[idx] = r;
    ptfeat[idx] = p;
}

__global__ __launch_bounds__(256) void k_stats1(const void* __restrict__ W1, const void* __restrict__ b1,
                                                const u32* dflag, const u32* nkept,
                                                const float4* __restrict__ ptfeat,
                                                double* sum1, double* sq1) {
    __shared__ float sW[4][64];
    __shared__ float sb[64];
    __shared__ float ss[64];
    __shared__ float sq[64];
    int t = threadIdx.x;
    bool bf = *dflag != 0;
    if (t < 64) { sb[t] = ld1(b1, t, bf); ss[t] = 0.f; sq[t] = 0.f; }
    sW[t >> 6][t & 63] = ld1(W1, t, bf);
    __syncthreads();
    int P = (int)min(*nkept, (u32)PCAP);
    int i = blockIdx.x * 256 + t;
    if (i < P) {
        float4 f = ptfeat[i];
        #pragma unroll 8
        for (int c = 0; c < 64; c++) {
            float zv = f.x * sW[0][c] + f.y * sW[1][c] + f.z * sW[2][c] + f.w * sW[3][c] + sb[c];
            atomicAdd(&ss[c], zv);
            atomicAdd(&sq[c], zv * zv);
        }
    }
    __syncthreads();
    if (t < 64) {
        atomicAdd(&sum1[t], (double)ss[t]);
        atomicAdd(&sq1[t], (double)sq[t]);
    }
}

__global__ void k_fin1(const void* __restrict__ b1, const void* __restrict__ g1, const void* __restrict__ be1,
                       const void* __restrict__ W2, const void* __restrict__ b2,
                       const u32* dflag, const u32* nkept, const double* sum1, const double* sq1,
                       float* mu1, float* rs1, float* z2z) {
    __shared__ float h1s[64];
    int c = threadIdx.x; // 64 threads
    bool bf = *dflag != 0;
    int P = (int)min(*nkept, (u32)PCAP);
    double Zn = (double)(NTOT - P);
    double bb = (double)ld1(b1, c, bf);
    double mu = (sum1[c] + Zn * bb) / (double)NTOT;
    double var = (sq1[c] + Zn * bb * bb) / (double)NTOT - mu * mu;
    if (var < 0.0) var = 0.0;
    float rs = (float)(1.0 / sqrt(var + 1e-5));
    float muf = (float)mu;
    mu1[c] = muf;
    rs1[c] = rs;
    float h = ((float)bb - muf) * rs * ld1(g1, c, bf) + ld1(be1, c, bf);
    h1s[c] = h > 0.f ? h : 0.f;
    __syncthreads();
    float acc = ld1(b2, c, bf);
    for (int j = 0; j < 64; j++) acc += h1s[j] * ld1(W2, j * 64 + c, bf);
    z2z[c] = acc;
}

__global__ __launch_bounds__(256) void k_stats2(const void* __restrict__ W1, const void* __restrict__ b1,
                                                const void* __restrict__ g1, const void* __restrict__ be1,
                                                const void* __restrict__ W2, const void* __restrict__ b2,
                                                const u32* dflag, const u32* nkept,
                                                const float4* __restrict__ ptfeat,
                                                const float* __restrict__ mu1, const float* __restrict__ rs1,
                                                double* sum2, double* sq2) {
    __shared__ __align__(16) float sW2[64 * 64];
    __shared__ float sW1[4][64], sb1[64], sg1[64], sbe1[64], smu[64], srs[64], sb2[64];
    __shared__ float ss[64], sq[64];
    int t = threadIdx.x;
    bool bf = *dflag != 0;
    for (int j = t; j < 4096; j += 256) sW2[j] = ld1(W2, j, bf);
    sW1[t >> 6][t & 63] = ld1(W1, t, bf);
    if (t < 64) {
        sb1[t] = ld1(b1, t, bf); sg1[t] = ld1(g1, t, bf); sbe1[t] = ld1(be1, t, bf);
        smu[t] = mu1[t]; srs[t] = rs1[t]; sb2[t] = ld1(b2, t, bf);
        ss[t] = 0.f; sq[t] = 0.f;
    }
    __syncthreads();
    int P = (int)min(*nkept, (u32)PCAP);
    int i = blockIdx.x * 256 + t;
    if (i < P) {
        float4 f = ptfeat[i];
        float h1[64];
        #pragma unroll
        for (int c = 0; c < 64; c++) {
            float zv = f.x * sW1[0][c] + f.y * sW1[1][c] + f.z * sW1[2][c] + f.w * sW1[3][c] + sb1[c];
            float h = (zv - smu[c]) * srs[c] * sg1[c] + sbe1[c];
            h1[c] = h > 0.f ? h : 0.f;
        }
        for (int c = 0; c < 64; c += 4) {
            float a0 = sb2[c], a1 = sb2[c + 1], a2 = sb2[c + 2], a3 = sb2[c + 3];
            #pragma unroll
            for (int j = 0; j < 64; j++) {
                float4 wv = *(const float4*)&sW2[j * 64 + c];
                a0 += h1[j] * wv.x; a1 += h1[j] * wv.y; a2 += h1[j] * wv.z; a3 += h1[j] * wv.w;
            }
            atomicAdd(&ss[c], a0);     atomicAdd(&sq[c], a0 * a0);
            atomicAdd(&ss[c + 1], a1); atomicAdd(&sq[c + 1], a1 * a1);
            atomicAdd(&ss[c + 2], a2); atomicAdd(&sq[c + 2], a2 * a2);
            atomicAdd(&ss[c + 3], a3); atomicAdd(&sq[c + 3], a3 * a3);
        }
    }
    __syncthreads();
    if (t < 64) {
        atomicAdd(&sum2[t], (double)ss[t]);
        atomicAdd(&sq2[t], (double)sq[t]);
    }
}

__global__ void k_fin2(const u32* nkept, const double* sum2, const double* sq2,
                       const float* z2z, float* mu2, float* rs2) {
    int c = threadIdx.x;
    int P = (int)min(*nkept, (u32)PCAP);
    double Zn = (double)(NTOT - P);
    double zz = (double)z2z[c];
    double mu = (sum2[c] + Zn * zz) / (double)NTOT;
    double var = (sq2[c] + Zn * zz * zz) / (double)NTOT - mu * mu;
    if (var < 0.0) var = 0.0;
    mu2[c] = (float)mu;
    rs2[c] = (float)(1.0 / sqrt(var + 1e-5));
}

__global__ __launch_bounds__(256) void k_final(const void* __restrict__ W1, const void* __restrict__ b1,
                                               const void* __restrict__ g1, const void* __restrict__ be1,
                                               const void* __restrict__ W2, const void* __restrict__ b2,
                                               const void* __restrict__ g2, const void* __restrict__ be2,
                                               const void* __restrict__ W3, const void* __restrict__ b3,
                                               const u32* dflag, const u32* nkept,
                                               const float4* __restrict__ ptfeat,
                                               const int* __restrict__ ptvid,
                                               const float* __restrict__ mu1, const float* __restrict__ rs1,
                                               const float* __restrict__ mu2, const float* __restrict__ rs2,
                                               u32* maxbuf) {
    __shared__ __align__(16) float sW2[64 * 64];
    __shared__ __align__(16) float sW3[64 * 128];
    __shared__ float sW1[4][64], sb1[64], sg1[64], sbe1[64], smu1[64], srs1[64];
    __shared__ float sb2[64], sg2[64], sbe2[64], smu2[64], srs2[64], sb3[128];
    int t = threadIdx.x;
    bool bf = *dflag != 0;
    for (int j = t; j < 4096; j += 256) sW2[j] = ld1(W2, j, bf);
    for (int j = t; j < 8192; j += 256) sW3[j] = ld1(W3, j, bf);
    sW1[t >> 6][t & 63] = ld1(W1, t, bf);
    if (t < 64) {
        sb1[t] = ld1(b1, t, bf); sg1[t] = ld1(g1, t, bf); sbe1[t] = ld1(be1, t, bf);
        smu1[t] = mu1[t]; srs1[t] = rs1[t];
        sb2[t] = ld1(b2, t, bf); sg2[t] = ld1(g2, t, bf); sbe2[t] = ld1(be2, t, bf);
        smu2[t] = mu2[t]; srs2[t] = rs2[t];
    }
    if (t < 128) sb3[t] = ld1(b3, t, bf);
    __syncthreads();
    int P = (int)min(*nkept, (u32)PCAP);
    int i = blockIdx.x * 256 + t;
    if (i >= P) return;
    float4 f = ptfeat[i];
    int vid = ptvid[i];
    float h1[64], h2[64];
    #pragma unroll
    for (int c = 0; c < 64; c++) {
        float zv = f.x * sW1[0][c] + f.y * sW1[1][c] + f.z * sW1[2][c] + f.w * sW1[3][c] + sb1[c];
        float h = (zv - smu1[c]) * srs1[c] * sg1[c] + sbe1[c];
        h1[c] = h > 0.f ? h : 0.f;
    }
    for (int c = 0; c < 64; c += 4) {
        float a0 = sb2[c], a1 = sb2[c + 1], a2 = sb2[c + 2], a3 = sb2[c + 3];
        #pragma unroll
        for (int j = 0; j < 64; j++) {
            float4 wv = *(const float4*)&sW2[j * 64 + c];
            a0 += h1[j] * wv.x; a1 += h1[j] * wv.y; a2 += h1[j] * wv.z; a3 += h1[j] * wv.w;
        }
        float z0 = (a0 - smu2[c]) * srs2[c] * sg2[c] + sbe2[c];
        float z1 = (a1 - smu2[c + 1]) * srs2[c + 1] * sg2[c + 1] + sbe2[c + 1];
        float z2 = (a2 - smu2[c + 2]) * srs2[c + 2] * sg2[c + 2] + sbe2[c + 2];
        float z3 = (a3 - smu2[c + 3]) * srs2[c + 3] * sg2[c + 3] + sbe2[c + 3];
        h2[c] = z0 > 0.f ? z0 : 0.f;
        h2[c + 1] = z1 > 0.f ? z1 : 0.f;
        h2[c + 2] = z2 > 0.f ? z2 : 0.f;
        h2[c + 3] = z3 > 0.f ? z3 : 0.f;
    }
    u32* dst = maxbuf + (size_t)vid * 128;
    for (int c = 0; c < 128; c += 4) {
        float a0 = sb3[c], a1 = sb3[c + 1], a2 = sb3[c + 2], a3 = sb3[c + 3];
        #pragma unroll
        for (int j = 0; j < 64; j++) {
            float4 wv = *(const float4*)&sW3[j * 128 + c];
            a0 += h2[j] * wv.x; a1 += h2[j] * wv.y; a2 += h2[j] * wv.z; a3 += h2[j] * wv.w;
        }
        atomicMax(&dst[c], encf(a0));
        atomicMax(&dst[c + 1], encf(a1));
        atomicMax(&dst[c + 2], encf(a2));
        atomicMax(&dst[c + 3], encf(a3));
    }
}

__global__ void k_out(const u32* __restrict__ maxbuf, const u32* dflag, void* __restrict__ out) {
    int i = blockIdx.x * 256 + threadIdx.x;
    bool bf = *dflag != 0;
    if (i < OUTV) st1(out, (size_t)i, decf(maxbuf[i]), bf);
}

// ---------- launch ----------
extern "C" void kernel_launch(void* const* d_in, const int* in_sizes, int n_in,
                              void* d_out, int out_size, void* d_ws, size_t ws_size,
                              hipStream_t stream) {
    const void* pts = d_in[0];
    const void* W1 = d_in[1];
    const void* b1 = d_in[2];
    const void* g1 = d_in[3];
    const void* be1 = d_in[4];
    const void* W2 = d_in[5];
    const void* b2 = d_in[6];
    const void* g2 = d_in[7];
    const void* be2 = d_in[8];
    const void* W3 = d_in[9];
    const void* b3 = d_in[10];

    char* ws = (char*)d_ws;
    size_t off = 0;
    auto alloc = [&](size_t bytes) -> size_t {
        size_t o = off;
        off = (off + bytes + 255) & ~(size_t)255;
        return o;
    };
    u32* count = (u32*)(ws + alloc((size_t)NVOX * 4));
    u16* prefix = (u16*)(ws + alloc((size_t)NVOX * 2));
    u32* maxbuf = (u32*)(ws + alloc((size_t)OUTV * 4));
    u32* bsums = (u32*)(ws + alloc((size_t)SNB * 4));
    u32* boffs = (u32*)(ws + alloc((size_t)SNB * 4));
    size_t zstart = off;
    u32* slotctr = (u32*)(ws + alloc((size_t)MAXV * 4));
    u32* nkept = (u32*)(ws + alloc(256));
    double* sum1 = (double*)(ws + alloc(64 * 8));
    double* sq1 = (double*)(ws + alloc(64 * 8));
    double* sum2 = (double*)(ws + alloc(64 * 8));
    double* sq2 = (double*)(ws + alloc(64 * 8));
    size_t zend = off;
    int* firstkey = (int*)(ws + alloc(256));
    u32* totalocc = (u32*)(ws + alloc(256));
    u32* dflag = (u32*)(ws + alloc(256));
    float* mu1 = (float*)(ws + alloc(256));
    float* rs1 = (float*)(ws + alloc(256));
    float* z2z = (float*)(ws + alloc(256));
    float* mu2 = (float*)(ws + alloc(256));
    float* rs2 = (float*)(ws + alloc(256));
    int* ptvid = (int*)(ws + alloc((size_t)PCAP * 4));
    float4* ptfeat = (float4*)(ws + alloc((size_t)PCAP * 16));
    if (off > ws_size) return; // workspace too small

    hipMemsetAsync(count, 0, (size_t)NVOX * 4, stream);
    hipMemsetAsync(ws + zstart, 0, zend - zstart, stream);
    hipMemsetAsync(firstkey, 0x7F, 4, stream);

    k_detect<<<1, 256, 0, stream>>>(pts, dflag);
    k_initmax<<<(OUTV + 255) / 256, 256, 0, stream>>>(maxbuf);
    k_hist<<<(NPTS + 255) / 256, 256, 0, stream>>>(pts, dflag, count);
    k_scan1<<<SNB, 256, 0, stream>>>(count, bsums, firstkey);
    k_scan2<<<1, 256, 0, stream>>>(bsums, boffs, totalocc);
    k_scan3<<<SNB, 256, 0, stream>>>(count, boffs, dflag, prefix, d_out);
    k_pad<<<(MAXV + 255) / 256, 256, 0, stream>>>(totalocc, firstkey, dflag, d_out);
    k_gather<<<(NPTS + 255) / 256, 256, 0, stream>>>(pts, prefix, dflag, slotctr, nkept, ptvid, ptfeat);
    k_stats1<<<PCAP / 256, 256, 0, stream>>>(W1, b1, dflag, nkept, ptfeat, sum1, sq1);
    k_fin1<<<1, 64, 0, stream>>>(b1, g1, be1, W2, b2, dflag, nkept, sum1, sq1, mu1, rs1, z2z);
    k_stats2<<<PCAP / 256, 256, 0, stream>>>(W1, b1, g1, be1, W2, b2, dflag, nkept, ptfeat, mu1, rs1, sum2, sq2);
    k_fin2<<<1, 64, 0, stream>>>(nkept, sum2, sq2, z2z, mu2, rs2);
    k_final<<<PCAP / 256, 256, 0, stream>>>(W1, b1, g1, be1, W2, b2, g2, be2, W3, b3,
                                            dflag, nkept, ptfeat, ptvid, mu1, rs1, mu2, rs2, maxbuf);
    k_out<<<(OUTV + 255) / 256, 256, 0, stream>>>(maxbuf, dflag, d_out);
}

// Round 3
// 787.415 us; speedup vs baseline: 1.5519x; 1.5519x over previous
//
#include <hip/hip_runtime.h>
#include <stdint.h>

typedef unsigned int u32;
typedef unsigned short u16;

#define NPTS 1000000
#define DIMD 500
#define DIMH 500
#define DIMW 40
#define NVOX 10000000      // DIMD*DIMH*DIMW
#define MAXV 40000
#define MAXP 32
#define NTOT (MAXV * MAXP) // 1,280,000 rows in the flat MLP input
#define PCAP 131072        // capacity for kept points (expected ~42k)
#define OUTV (MAXV * 128)  // 5,120,000 voxel_out elements
#define SCHUNK 4096
#define SNB ((NVOX + SCHUNK - 1) / SCHUNK) // 2442 scan blocks
#define S1B 128            // stats1 grid
#define S2B 256            // stats2 grid

// ---------- helpers ----------
__device__ __forceinline__ float b2f(u16 h) { return __uint_as_float(((u32)h) << 16); }

__device__ __forceinline__ u16 f2b(float f) {
    u32 u = __float_as_uint(f);
    if ((u & 0x7F800000u) == 0x7F800000u) {           // inf / nan
        u16 h = (u16)(u >> 16);
        if (u & 0x007FFFFFu) h |= 0x40;               // quiet nan
        return h;
    }
    u32 lsb = (u >> 16) & 1u;
    return (u16)((u + 0x7FFFu + lsb) >> 16);          // round-to-nearest-even
}

// dtype-adaptive element load/store. bf==true -> bf16 (u16), else f32.
__device__ __forceinline__ float ld1(const void* p, int i, bool bf) {
    return bf ? b2f(((const u16*)p)[i]) : ((const float*)p)[i];
}
__device__ __forceinline__ float4 ld4(const void* p, int i4, bool bf) {
    if (bf) {
        ushort4 q = ((const ushort4*)p)[i4];
        return make_float4(b2f(q.x), b2f(q.y), b2f(q.z), b2f(q.w));
    }
    return ((const float4*)p)[i4];
}
__device__ __forceinline__ void st1(void* p, size_t i, float v, bool bf) {
    if (bf) ((u16*)p)[i] = f2b(v);
    else ((float*)p)[i] = v;
}

// monotone order-preserving f32 <-> u32 for atomicMax
__device__ __forceinline__ u32 encf(float f) {
    u32 u = __float_as_uint(f);
    return (u & 0x80000000u) ? ~u : (u | 0x80000000u);
}
__device__ __forceinline__ float decf(u32 u) {
    u32 b = (u & 0x80000000u) ? (u & 0x7FFFFFFFu) : ~u;
    return __uint_as_float(b);
}

// exact replica of ((xyz - RANGE_MIN)/VOXEL_SIZE).astype(int32) + validity (f32 ops)
__device__ __forceinline__ bool pkey(float x, float y, float z, int& key) {
    float fx = (x - (-50.0f)) / 0.2f;
    float fy = (y - (-50.0f)) / 0.2f;
    float fz = (z - (-3.0f)) / 0.2f;
    int ix = (int)fx, iy = (int)fy, iz = (int)fz;
    if (ix < 0 || ix >= DIMD || iy < 0 || iy >= DIMH || iz < 0 || iz >= DIMW) return false;
    key = ix * (DIMH * DIMW) + iy * DIMW + iz;
    return true;
}

// ---------- kernels ----------

// Detect input dtype. Even-indexed u16s of `points`: bf16 data -> bf16 values of
// coords in [-50,50] (f32 exponent field ~[90,140]); f32 data -> random low
// mantissa halves (~20% in window).
__global__ void k_detect(const void* pts, u32* dflag) {
    __shared__ int s[256];
    int t = threadIdx.x;
    const u16* p = (const u16*)pts;
    int good = 0;
    for (int i = 0; i < 16; i++) {
        u16 v = p[(size_t)(t * 16 + i) * 2];
        int e = (v >> 7) & 0xFF;
        if (e >= 90 && e <= 140) good++;
    }
    s[t] = good;
    __syncthreads();
    for (int o = 128; o > 0; o >>= 1) {
        if (t < o) s[t] += s[t + o];
        __syncthreads();
    }
    if (t == 0) *dflag = (s[0] >= (4096 * 3) / 5) ? 1u : 0u;
}

__global__ void k_initmax(u32* maxbuf) {
    int i = blockIdx.x * 256 + threadIdx.x;
    if (i < OUTV) maxbuf[i] = 0x007FFFFFu; // encf(-inf)
}

__global__ void k_hist(const void* __restrict__ pts, const u32* dflag, u32* __restrict__ count) {
    int i = blockIdx.x * 256 + threadIdx.x;
    if (i >= NPTS) return;
    bool bf = *dflag != 0;
    float4 p = ld4(pts, i, bf);
    int key;
    if (pkey(p.x, p.y, p.z, key)) atomicAdd(&count[key], 1u);
}

__global__ void k_scan1(const u32* __restrict__ count, u32* bsums, int* firstkey) {
    __shared__ int s[256];
    __shared__ int sm[256];
    int t = threadIdx.x;
    long base = (long)blockIdx.x * SCHUNK + (long)t * 16;
    int tot = 0, mn = 0x7FFFFFFF;
    for (int i = 0; i < 16; i++) {
        long k = base + i;
        if (k < NVOX && count[k]) { tot++; if ((int)k < mn) mn = (int)k; }
    }
    s[t] = tot; sm[t] = mn;
    __syncthreads();
    for (int o = 128; o > 0; o >>= 1) {
        if (t < o) { s[t] += s[t + o]; sm[t] = min(sm[t], sm[t + o]); }
        __syncthreads();
    }
    if (t == 0) {
        bsums[blockIdx.x] = (u32)s[0];
        if (sm[0] != 0x7FFFFFFF) atomicMin(firstkey, sm[0]);
    }
}

__global__ void k_scan2(const u32* __restrict__ bsums, u32* boffs, u32* totalocc) {
    __shared__ int s[256];
    int t = threadIdx.x;
    const int per = (SNB + 255) / 256;
    int st = t * per, en = min(st + per, (int)SNB);
    int tot = 0;
    for (int i = st; i < en; i++) tot += (int)bsums[i];
    s[t] = tot;
    __syncthreads();
    for (int o = 1; o < 256; o <<= 1) {
        int v = (t >= o) ? s[t - o] : 0;
        __syncthreads();
        s[t] += v;
        __syncthreads();
    }
    int run = s[t] - tot;
    for (int i = st; i < en; i++) { boffs[i] = (u32)run; run += (int)bsums[i]; }
    if (t == 255) *totalocc = (u32)s[255];
}

__global__ void k_scan3(const u32* __restrict__ count, const u32* __restrict__ boffs,
                        const u32* dflag, u16* __restrict__ prefix, void* __restrict__ out) {
    __shared__ int s[256];
    int t = threadIdx.x;
    bool bf = *dflag != 0;
    long base = (long)blockIdx.x * SCHUNK + (long)t * 16;
    int tot = 0;
    for (int i = 0; i < 16; i++) {
        long k = base + i;
        if (k < NVOX && count[k]) tot++;
    }
    s[t] = tot;
    __syncthreads();
    for (int o = 1; o < 256; o <<= 1) {
        int v = (t >= o) ? s[t - o] : 0;
        __syncthreads();
        s[t] += v;
        __syncthreads();
    }
    int run = (int)boffs[blockIdx.x] + s[t] - tot;
    for (int i = 0; i < 16; i++) {
        long k = base + i;
        if (k >= NVOX) break;
        u32 c = count[k];
        prefix[k] = (u16)min(run, 65535);
        if (c) {
            if (run < MAXV) {
                int kk = (int)k;
                int ix = kk / 20000;
                int rem = kk - ix * 20000;
                int iy = rem / 40;
                int iz = rem - iy * 40;
                size_t base_o = (size_t)OUTV + (size_t)run * 4;
                st1(out, base_o + 0, 0.0f, bf);
                st1(out, base_o + 1, (float)ix, bf);
                st1(out, base_o + 2, (float)iy, bf);
                st1(out, base_o + 3, (float)iz, bf);
            }
            run++;
        }
    }
}

__global__ void k_pad(const u32* totalocc, const int* firstkey, const u32* dflag, void* out) {
    int r = blockIdx.x * 256 + threadIdx.x;
    if (r >= MAXV) return;
    if (r < (int)(*totalocc)) return;
    bool bf = *dflag != 0;
    int fk = *firstkey;
    if (fk >= NVOX) fk = 0;
    int ix = fk / 20000, rem = fk - ix * 20000, iy = rem / 40, iz = rem - iy * 40;
    size_t base_o = (size_t)OUTV + (size_t)r * 4;
    st1(out, base_o + 0, 0.0f, bf);
    st1(out, base_o + 1, (float)ix, bf);
    st1(out, base_o + 2, (float)iy, bf);
    st1(out, base_o + 3, (float)iz, bf);
}

__global__ void k_gather(const void* __restrict__ pts, const u16* __restrict__ prefix,
                         const u32* dflag, u32* slotctr, u32* nkept, int* ptvid, float4* ptfeat) {
    int i = blockIdx.x * 256 + threadIdx.x;
    if (i >= NPTS) return;
    bool bf = *dflag != 0;
    float4 p = ld4(pts, i, bf);
    int key;
    if (!pkey(p.x, p.y, p.z, key)) return;
    int r = (int)prefix[key];
    if (r >= MAXV) return;
    u32 slot = atomicAdd(&slotctr[r], 1u);
    if (slot >= MAXP) return;
    u32 idx = atomicAdd(nkept, 1u);
    if (idx >= PCAP) return;
    ptvid[idx] = r;
    ptfeat[idx] = p;
}

// stats over layer-1 pre-BN activations: lane = channel, register accumulation,
// per-block partials (no atomics).
__global__ __launch_bounds__(256) void k_stats1(const void* __restrict__ W1, const void* __restrict__ b1,
                                                const u32* dflag, const u32* nkept,
                                                const float4* __restrict__ ptfeat,
                                                double* __restrict__ part1) {
    __shared__ double ls[4][64], lq[4][64];
    int t = threadIdx.x, lane = t & 63, w = t >> 6;
    bool bf = *dflag != 0;
    float w0 = ld1(W1, 0 * 64 + lane, bf);
    float w1 = ld1(W1, 1 * 64 + lane, bf);
    float w2 = ld1(W1, 2 * 64 + lane, bf);
    float w3 = ld1(W1, 3 * 64 + lane, bf);
    float bb = ld1(b1, lane, bf);
    int P = (int)min(*nkept, (u32)PCAP);
    int G = gridDim.x * 4;
    int gw = blockIdx.x * 4 + w;
    double s = 0.0, q = 0.0;
    for (int p = gw; p < P; p += G) {
        float4 f = ptfeat[p]; // wave-uniform address -> broadcast
        float z = f.x * w0 + f.y * w1 + f.z * w2 + f.w * w3 + bb;
        s += (double)z;
        q += (double)z * (double)z;
    }
    ls[w][lane] = s; lq[w][lane] = q;
    __syncthreads();
    if (t < 64) {
        double S = ls[0][t] + ls[1][t] + ls[2][t] + ls[3][t];
        double Q = lq[0][t] + lq[1][t] + lq[2][t] + lq[3][t];
        part1[(size_t)blockIdx.x * 128 + t] = S;
        part1[(size_t)blockIdx.x * 128 + 64 + t] = Q;
    }
}

__global__ void k_fin1(const void* __restrict__ b1, const void* __restrict__ g1, const void* __restrict__ be1,
                       const void* __restrict__ W2, const void* __restrict__ b2,
                       const u32* dflag, const u32* nkept, const double* __restrict__ part1,
                       float* mu1, float* rs1, float* z2z) {
    __shared__ float h1s[64];
    int c = threadIdx.x; // 64 threads
    bool bf = *dflag != 0;
    int P = (int)min(*nkept, (u32)PCAP);
    double S = 0.0, Q = 0.0;
    for (int b = 0; b < S1B; b++) {
        S += part1[(size_t)b * 128 + c];
        Q += part1[(size_t)b * 128 + 64 + c];
    }
    double Zn = (double)(NTOT - P);
    double bb = (double)ld1(b1, c, bf);
    double mu = (S + Zn * bb) / (double)NTOT;
    double var = (Q + Zn * bb * bb) / (double)NTOT - mu * mu;
    if (var < 0.0) var = 0.0;
    float rs = (float)(1.0 / sqrt(var + 1e-5));
    float muf = (float)mu;
    mu1[c] = muf;
    rs1[c] = rs;
    float h = ((float)bb - muf) * rs * ld1(g1, c, bf) + ld1(be1, c, bf);
    h1s[c] = h > 0.f ? h : 0.f;
    __syncthreads();
    float acc = ld1(b2, c, bf);
    for (int j = 0; j < 64; j++) acc += h1s[j] * ld1(W2, j * 64 + c, bf);
    z2z[c] = acc;
}

// stats over layer-2 pre-BN: lane = channel, W2 column in registers,
// h1 shared intra-wave via LDS broadcast reads. No atomics.
__global__ __launch_bounds__(256) void k_stats2(const void* __restrict__ W1, const void* __restrict__ b1,
                                                const void* __restrict__ g1, const void* __restrict__ be1,
                                                const void* __restrict__ W2, const void* __restrict__ b2,
                                                const u32* dflag, const u32* nkept,
                                                const float4* __restrict__ ptfeat,
                                                const float* __restrict__ mu1, const float* __restrict__ rs1,
                                                double* __restrict__ part2) {
    __shared__ float h1buf[4][64];
    __shared__ double ls[4][64], lq[4][64];
    int t = threadIdx.x, lane = t & 63, w = t >> 6;
    bool bf = *dflag != 0;
    float w10 = ld1(W1, 0 * 64 + lane, bf);
    float w11 = ld1(W1, 1 * 64 + lane, bf);
    float w12 = ld1(W1, 2 * 64 + lane, bf);
    float w13 = ld1(W1, 3 * 64 + lane, bf);
    float bb1 = ld1(b1, lane, bf);
    float m1 = mu1[lane], r1 = rs1[lane];
    float gg1 = ld1(g1, lane, bf), bbe1 = ld1(be1, lane, bf);
    float bb2 = ld1(b2, lane, bf);
    float w2col[64];
    #pragma unroll
    for (int j = 0; j < 64; j++) w2col[j] = ld1(W2, j * 64 + lane, bf);
    int P = (int)min(*nkept, (u32)PCAP);
    int G = gridDim.x * 4;
    int gw = blockIdx.x * 4 + w;
    int niter = (P + G - 1) / G; // uniform across all waves
    double s = 0.0, q = 0.0;
    const float4* hb = (const float4*)&h1buf[w][0];
    for (int it = 0; it < niter; it++) {
        int p = gw + it * G;
        bool act = p < P; // wave-uniform
        if (act) {
            float4 f = ptfeat[p]; // broadcast
            float z1 = f.x * w10 + f.y * w11 + f.z * w12 + f.w * w13 + bb1;
            float h = (z1 - m1) * r1 * gg1 + bbe1;
            h1buf[w][lane] = h > 0.f ? h : 0.f;
        }
        __syncthreads();
        if (act) {
            float acc = bb2;
            #pragma unroll
            for (int jq = 0; jq < 16; jq++) {
                float4 hv = hb[jq]; // wave-uniform address -> LDS broadcast
                acc += hv.x * w2col[4 * jq] + hv.y * w2col[4 * jq + 1]
                     + hv.z * w2col[4 * jq + 2] + hv.w * w2col[4 * jq + 3];
            }
            s += (double)acc;
            q += (double)acc * (double)acc;
        }
        __syncthreads();
    }
    ls[w][lane] = s; lq[w][lane] = q;
    __syncthreads();
    if (t < 64) {
        double S = ls[0][t] + ls[1][t] + ls[2][t] + ls[3][t];
        double Q = lq[0][t] + lq[1][t] + lq[2][t] + lq[3][t];
        part2[(size_t)blockIdx.x * 128 + t] = S;
        part2[(size_t)blockIdx.x * 128 + 64 + t] = Q;
    }
}

__global__ void k_fin2(const u32* nkept, const double* __restrict__ part2,
                       const float* z2z, float* mu2, float* rs2) {
    int c = threadIdx.x; // 64 threads
    int P = (int)min(*nkept, (u32)PCAP);
    double S = 0.0, Q = 0.0;
    for (int b = 0; b < S2B; b++) {
        S += part2[(size_t)b * 128 + c];
        Q += part2[(size_t)b * 128 + 64 + c];
    }
    double Zn = (double)(NTOT - P);
    double zz = (double)z2z[c];
    double mu = (S + Zn * zz) / (double)NTOT;
    double var = (Q + Zn * zz * zz) / (double)NTOT - mu * mu;
    if (var < 0.0) var = 0.0;
    mu2[c] = (float)mu;
    rs2[c] = (float)(1.0 / sqrt(var + 1e-5));
}

__global__ __launch_bounds__(256) void k_final(const void* __restrict__ W1, const void* __restrict__ b1,
                                               const void* __restrict__ g1, const void* __restrict__ be1,
                                               const void* __restrict__ W2, const void* __restrict__ b2,
                                               const void* __restrict__ g2, const void* __restrict__ be2,
                                               const void* __restrict__ W3, const void* __restrict__ b3,
                                               const u32* dflag, const u32* nkept,
                                               const float4* __restrict__ ptfeat,
                                               const int* __restrict__ ptvid,
                                               const float* __restrict__ mu1, const float* __restrict__ rs1,
                                               const float* __restrict__ mu2, const float* __restrict__ rs2,
                                               u32* maxbuf) {
    __shared__ __align__(16) float sW2[64 * 64];
    __shared__ __align__(16) float sW3[64 * 128];
    __shared__ float sW1[4][64], sb1[64], sg1[64], sbe1[64], smu1[64], srs1[64];
    __shared__ float sb2[64], sg2[64], sbe2[64], smu2[64], srs2[64], sb3[128];
    int t = threadIdx.x;
    bool bf = *dflag != 0;
    for (int j = t; j < 4096; j += 256) sW2[j] = ld1(W2, j, bf);
    for (int j = t; j < 8192; j += 256) sW3[j] = ld1(W3, j, bf);
    sW1[t >> 6][t & 63] = ld1(W1, t, bf);
    if (t < 64) {
        sb1[t] = ld1(b1, t, bf); sg1[t] = ld1(g1, t, bf); sbe1[t] = ld1(be1, t, bf);
        smu1[t] = mu1[t]; srs1[t] = rs1[t];
        sb2[t] = ld1(b2, t, bf); sg2[t] = ld1(g2, t, bf); sbe2[t] = ld1(be2, t, bf);
        smu2[t] = mu2[t]; srs2[t] = rs2[t];
    }
    if (t < 128) sb3[t] = ld1(b3, t, bf);
    __syncthreads();
    int P = (int)min(*nkept, (u32)PCAP);
    int i = blockIdx.x * 256 + t;
    if (i >= P) return;
    float4 f = ptfeat[i];
    int vid = ptvid[i];
    float h1[64], h2[64];
    #pragma unroll
    for (int c = 0; c < 64; c++) {
        float zv = f.x * sW1[0][c] + f.y * sW1[1][c] + f.z * sW1[2][c] + f.w * sW1[3][c] + sb1[c];
        float h = (zv - smu1[c]) * srs1[c] * sg1[c] + sbe1[c];
        h1[c] = h > 0.f ? h : 0.f;
    }
    for (int c = 0; c < 64; c += 4) {
        float a0 = sb2[c], a1 = sb2[c + 1], a2 = sb2[c + 2], a3 = sb2[c + 3];
        #pragma unroll
        for (int j = 0; j < 64; j++) {
            float4 wv = *(const float4*)&sW2[j * 64 + c];
            a0 += h1[j] * wv.x; a1 += h1[j] * wv.y; a2 += h1[j] * wv.z; a3 += h1[j] * wv.w;
        }
        float z0 = (a0 - smu2[c]) * srs2[c] * sg2[c] + sbe2[c];
        float z1 = (a1 - smu2[c + 1]) * srs2[c + 1] * sg2[c + 1] + sbe2[c + 1];
        float z2 = (a2 - smu2[c + 2]) * srs2[c + 2] * sg2[c + 2] + sbe2[c + 2];
        float z3 = (a3 - smu2[c + 3]) * srs2[c + 3] * sg2[c + 3] + sbe2[c + 3];
        h2[c] = z0 > 0.f ? z0 : 0.f;
        h2[c + 1] = z1 > 0.f ? z1 : 0.f;
        h2[c + 2] = z2 > 0.f ? z2 : 0.f;
        h2[c + 3] = z3 > 0.f ? z3 : 0.f;
    }
    u32* dst = maxbuf + (size_t)vid * 128;
    for (int c = 0; c < 128; c += 4) {
        float a0 = sb3[c], a1 = sb3[c + 1], a2 = sb3[c + 2], a3 = sb3[c + 3];
        #pragma unroll
        for (int j = 0; j < 64; j++) {
            float4 wv = *(const float4*)&sW3[j * 128 + c];
            a0 += h2[j] * wv.x; a1 += h2[j] * wv.y; a2 += h2[j] * wv.z; a3 += h2[j] * wv.w;
        }
        atomicMax(&dst[c], encf(a0));
        atomicMax(&dst[c + 1], encf(a1));
        atomicMax(&dst[c + 2], encf(a2));
        atomicMax(&dst[c + 3], encf(a3));
    }
}

__global__ void k_out(const u32* __restrict__ maxbuf, const u32* dflag, void* __restrict__ out) {
    int i = blockIdx.x * 256 + threadIdx.x;
    bool bf = *dflag != 0;
    if (i < OUTV) st1(out, (size_t)i, decf(maxbuf[i]), bf);
}

// ---------- launch ----------
extern "C" void kernel_launch(void* const* d_in, const int* in_sizes, int n_in,
                              void* d_out, int out_size, void* d_ws, size_t ws_size,
                              hipStream_t stream) {
    const void* pts = d_in[0];
    const void* W1 = d_in[1];
    const void* b1 = d_in[2];
    const void* g1 = d_in[3];
    const void* be1 = d_in[4];
    const void* W2 = d_in[5];
    const void* b2 = d_in[6];
    const void* g2 = d_in[7];
    const void* be2 = d_in[8];
    const void* W3 = d_in[9];
    const void* b3 = d_in[10];

    char* ws = (char*)d_ws;
    size_t off = 0;
    auto alloc = [&](size_t bytes) -> size_t {
        size_t o = off;
        off = (off + bytes + 255) & ~(size_t)255;
        return o;
    };
    u32* count = (u32*)(ws + alloc((size_t)NVOX * 4));
    u16* prefix = (u16*)(ws + alloc((size_t)NVOX * 2));
    u32* maxbuf = (u32*)(ws + alloc((size_t)OUTV * 4));
    u32* bsums = (u32*)(ws + alloc((size_t)SNB * 4));
    u32* boffs = (u32*)(ws + alloc((size_t)SNB * 4));
    size_t zstart = off;
    u32* slotctr = (u32*)(ws + alloc((size_t)MAXV * 4));
    u32* nkept = (u32*)(ws + alloc(256));
    size_t zend = off;
    double* part1 = (double*)(ws + alloc((size_t)S1B * 128 * 8));
    double* part2 = (double*)(ws + alloc((size_t)S2B * 128 * 8));
    int* firstkey = (int*)(ws + alloc(256));
    u32* totalocc = (u32*)(ws + alloc(256));
    u32* dflag = (u32*)(ws + alloc(256));
    float* mu1 = (float*)(ws + alloc(256));
    float* rs1 = (float*)(ws + alloc(256));
    float* z2z = (float*)(ws + alloc(256));
    float* mu2 = (float*)(ws + alloc(256));
    float* rs2 = (float*)(ws + alloc(256));
    int* ptvid = (int*)(ws + alloc((size_t)PCAP * 4));
    float4* ptfeat = (float4*)(ws + alloc((size_t)PCAP * 16));
    if (off > ws_size) return; // workspace too small

    hipMemsetAsync(count, 0, (size_t)NVOX * 4, stream);
    hipMemsetAsync(ws + zstart, 0, zend - zstart, stream);
    hipMemsetAsync(firstkey, 0x7F, 4, stream);

    k_detect<<<1, 256, 0, stream>>>(pts, dflag);
    k_initmax<<<(OUTV + 255) / 256, 256, 0, stream>>>(maxbuf);
    k_hist<<<(NPTS + 255) / 256, 256, 0, stream>>>(pts, dflag, count);
    k_scan1<<<SNB, 256, 0, stream>>>(count, bsums, firstkey);
    k_scan2<<<1, 256, 0, stream>>>(bsums, boffs, totalocc);
    k_scan3<<<SNB, 256, 0, stream>>>(count, boffs, dflag, prefix, d_out);
    k_pad<<<(MAXV + 255) / 256, 256, 0, stream>>>(totalocc, firstkey, dflag, d_out);
    k_gather<<<(NPTS + 255) / 256, 256, 0, stream>>>(pts, prefix, dflag, slotctr, nkept, ptvid, ptfeat);
    k_stats1<<<S1B, 256, 0, stream>>>(W1, b1, dflag, nkept, ptfeat, part1);
    k_fin1<<<1, 64, 0, stream>>>(b1, g1, be1, W2, b2, dflag, nkept, part1, mu1, rs1, z2z);
    k_stats2<<<S2B, 256, 0, stream>>>(W1, b1, g1, be1, W2, b2, dflag, nkept, ptfeat, mu1, rs1, part2);
    k_fin2<<<1, 64, 0, stream>>>(nkept, part2, z2z, mu2, rs2);
    k_final<<<PCAP / 256, 256, 0, stream>>>(W1, b1, g1, be1, W2, b2, g2, be2, W3, b3,
                                            dflag, nkept, ptfeat, ptvid, mu1, rs1, mu2, rs2, maxbuf);
    k_out<<<(OUTV + 255) / 256, 256, 0, stream>>>(maxbuf, dflag, d_out);
}